// Round 4
// baseline (823.058 us; speedup 1.0000x reference)
//
#include <hip/hip_runtime.h>
#include <math.h>

#define ALPHA_F 0.7f
#define NSTATES 64
#define BB 4
#define SS 2048
#define VV 8192
#define ROWS (BB*SS)
#define CHUNK 32
#define NCHUNK (SS/CHUNK)   // 64
#define MASKW (VV/32)       // 256 u32 words per state

// ---------------- K-1: zero the accumulators (avoid hipMemsetAsync in capture) ----
__global__ void k_zero(float* __restrict__ acc) {
    acc[0] = 0.f; acc[1] = 0.f; acc[2] = 0.f; acc[3] = 0.f;
}

// ---------------- K0: reject bitmask per state ----------------
// bit v of state st set iff state_types[transition[st][v]] == -1
__global__ __launch_bounds__(256) void k_mask(const int* __restrict__ trans,
                                              const int* __restrict__ stypes,
                                              unsigned* __restrict__ rbits) {
    int st = blockIdx.x;
    int w  = threadIdx.x;                // word index 0..255
    const int* row = trans + (size_t)st * VV + w * 32;
    unsigned bits = 0u;
    #pragma unroll
    for (int k = 0; k < 32; ++k) {
        if (stypes[row[k]] == -1) bits |= (1u << k);
    }
    rbits[st * MASKW + w] = bits;
}

// ---------------- K1: row argmax of inputs (first-index tie-break) ----------------
__global__ __launch_bounds__(256) void k_argmax(const float* __restrict__ inputs,
                                                int* __restrict__ tokens) {
    int row = blockIdx.x;
    const float4* p = (const float4*)(inputs + (size_t)row * VV);
    float bv = -INFINITY;
    int   bi = 0x7fffffff;
    #pragma unroll
    for (int it = 0; it < VV / 4 / 256; ++it) {
        int i4 = it * 256 + threadIdx.x;
        float4 v = p[i4];
        int base = i4 * 4;
        if (v.x > bv) { bv = v.x; bi = base;     }
        if (v.y > bv) { bv = v.y; bi = base + 1; }
        if (v.z > bv) { bv = v.z; bi = base + 2; }
        if (v.w > bv) { bv = v.w; bi = base + 3; }
    }
    // wave (64-lane) reduce, keep smaller index on ties
    #pragma unroll
    for (int off = 1; off < 64; off <<= 1) {
        float ov = __shfl_xor(bv, off);
        int   oi = __shfl_xor(bi, off);
        if (ov > bv || (ov == bv && oi < bi)) { bv = ov; bi = oi; }
    }
    __shared__ float swv[4];
    __shared__ int   swi[4];
    int wave = threadIdx.x >> 6;
    int lane = threadIdx.x & 63;
    if (lane == 0) { swv[wave] = bv; swi[wave] = bi; }
    __syncthreads();
    if (threadIdx.x == 0) {
        float v = swv[0]; int i = swi[0];
        #pragma unroll
        for (int k = 1; k < 4; ++k) {
            if (swv[k] > v || (swv[k] == v && swi[k] < i)) { v = swv[k]; i = swi[k]; }
        }
        tokens[row] = i;
    }
}

// ---------------- K2a: per-(batch,chunk) 64->64 transition map ----------------
__global__ __launch_bounds__(64) void k_maps(const int* __restrict__ trans,
                                             const int* __restrict__ tokens,
                                             int* __restrict__ maps) {
    __shared__ int tk[CHUNK];
    int bc = blockIdx.x;                  // b*NCHUNK + c
    int b = bc / NCHUNK, c = bc % NCHUNK;
    if (threadIdx.x < CHUNK)
        tk[threadIdx.x] = tokens[b * SS + c * CHUNK + threadIdx.x];
    __syncthreads();
    int s = threadIdx.x;                  // start state
    #pragma unroll 1
    for (int j = 0; j < CHUNK; ++j)
        s = trans[(size_t)s * VV + tk[j]];
    maps[bc * 64 + threadIdx.x] = s;
}

// ---------------- K2b: compose maps from state 0, emit per-step states ----------------
__global__ __launch_bounds__(64) void k_states(const int* __restrict__ trans,
                                               const int* __restrict__ tokens,
                                               const int* __restrict__ maps,
                                               int* __restrict__ state_ids) {
    int b = blockIdx.x;
    __shared__ int sigma[NCHUNK];
    if (threadIdx.x == 0) {
        int s = 0;
        for (int c = 0; c < NCHUNK; ++c) {
            sigma[c] = s;
            s = maps[(b * NCHUNK + c) * 64 + s];
        }
    }
    __syncthreads();
    int c = threadIdx.x;                  // one chunk per thread (NCHUNK==64)
    int s = sigma[c];
    const int* tk = tokens + b * SS + c * CHUNK;
    #pragma unroll 1
    for (int j = 0; j < CHUNK; ++j) {
        state_ids[b * SS + c * CHUNK + j] = s;   // state BEFORE consuming token j
        s = trans[(size_t)s * VV + tk[j]];
    }
}

// ---------------- K3: per-row online softmax stats + CE ----------------
__global__ __launch_bounds__(256) void k_main(const float* __restrict__ preds,
                                              const int* __restrict__ targets,
                                              const int* __restrict__ state_ids,
                                              const unsigned* __restrict__ rbits,
                                              float* __restrict__ acc) {
    int row = blockIdx.x;
    int state = state_ids[row];
    int tgt   = targets[row];

    __shared__ unsigned mask[MASKW];
    mask[threadIdx.x] = rbits[state * MASKW + threadIdx.x];
    __syncthreads();

    const float4* p = (const float4*)(preds + (size_t)row * VV);
    float m = -INFINITY, sum = 0.f, rsum = 0.f;
    #pragma unroll
    for (int it = 0; it < VV / 4 / 256; ++it) {
        int i4 = it * 256 + threadIdx.x;
        float4 v = p[i4];
        int base = i4 * 4;
        float xs[4] = {v.x, v.y, v.z, v.w};
        #pragma unroll
        for (int k = 0; k < 4; ++k) {
            float x = xs[k];
            int vi = base + k;
            float rej = (float)((mask[vi >> 5] >> (vi & 31)) & 1u);
            if (x > m) {
                float sc = __expf(m - x);
                sum *= sc; rsum *= sc; m = x;
            }
            float e = __expf(x - m);
            sum += e;
            rsum += rej * e;
        }
    }
    // wave reduce (64 lanes)
    #pragma unroll
    for (int off = 1; off < 64; off <<= 1) {
        float om = __shfl_xor(m,    off);
        float os = __shfl_xor(sum,  off);
        float orr= __shfl_xor(rsum, off);
        float nm = fmaxf(m, om);
        float s1 = __expf(m  - nm);
        float s2 = __expf(om - nm);
        sum  = sum  * s1 + os  * s2;
        rsum = rsum * s1 + orr * s2;
        m = nm;
    }
    __shared__ float sm[4], ssv[4], sr[4];
    int wave = threadIdx.x >> 6, lane = threadIdx.x & 63;
    if (lane == 0) { sm[wave] = m; ssv[wave] = sum; sr[wave] = rsum; }
    __syncthreads();
    if (threadIdx.x == 0) {
        float M = sm[0], Sv = ssv[0], R = sr[0];
        #pragma unroll
        for (int i = 1; i < 4; ++i) {
            float nm = fmaxf(M, sm[i]);
            float s1 = __expf(M - nm), s2 = __expf(sm[i] - nm);
            Sv = Sv * s1 + ssv[i] * s2;
            R  = R  * s1 + sr[i]  * s2;
            M = nm;
        }
        float ptgt = preds[(size_t)row * VV + tgt];
        float lse  = M + __logf(Sv);
        float ce   = lse - ptgt;
        float w    = ((mask[tgt >> 5] >> (tgt & 31)) & 1u) ? 0.05f : 1.0f;
        float inv  = R / Sv;
        atomicAdd(&acc[0], ce * w);
        atomicAdd(&acc[1], w);
        atomicAdd(&acc[2], inv);
    }
}

// ---------------- K4: finalize scalar ----------------
__global__ void k_final(const float* __restrict__ acc, float* __restrict__ out) {
    float wce = acc[0] / (acc[1] + 1e-6f);
    float inv = acc[2] / (float)ROWS;
    float sp  = -__logf(1.0f - inv + 1e-6f);
    out[0] = ALPHA_F * wce + (1.0f - ALPHA_F) * sp;
}

extern "C" void kernel_launch(void* const* d_in, const int* in_sizes, int n_in,
                              void* d_out, int out_size, void* d_ws, size_t ws_size,
                              hipStream_t stream) {
    const float* preds   = (const float*)d_in[0];
    const int*   targets = (const int*)d_in[1];
    const float* inputs  = (const float*)d_in[2];
    const int*   trans   = (const int*)d_in[3];
    const int*   stypes  = (const int*)d_in[4];
    float* out = (float*)d_out;

    char* ws = (char*)d_ws;
    int*      tokens    = (int*)(ws);                 // 32 KB
    int*      state_ids = (int*)(ws + 32768);         // 32 KB
    int*      maps      = (int*)(ws + 65536);         // 64 KB
    unsigned* rbits     = (unsigned*)(ws + 131072);   // 64 KB
    float*    acc       = (float*)(ws + 196608);      // 16 B

    k_zero  <<<1,             1, 0, stream>>>(acc);
    k_mask  <<<NSTATES,     256, 0, stream>>>(trans, stypes, rbits);
    k_argmax<<<ROWS,        256, 0, stream>>>(inputs, tokens);
    k_maps  <<<BB * NCHUNK,  64, 0, stream>>>(trans, tokens, maps);
    k_states<<<BB,           64, 0, stream>>>(trans, tokens, maps, state_ids);
    k_main  <<<ROWS,        256, 0, stream>>>(preds, targets, state_ids, rbits, acc);
    k_final <<<1,             1, 0, stream>>>(acc, out);
}